// Round 1
// 136.153 us; speedup vs baseline: 1.0727x; 1.0727x over previous
//
#include <hip/hip_runtime.h>
#include <math.h>

#define EPS_F 1e-8f

typedef __attribute__((ext_vector_type(8))) short bf16x8;
typedef __attribute__((ext_vector_type(4))) float f32x4;

// HW bf16 convert (RNE): plain __bf16 cast lets the compiler emit
// v_cvt_pk_bf16_f32 (1 inst / 2 elems) instead of 4 VALU ops/elem.
__device__ inline short f2bf(float f) {
    return (short)__builtin_bit_cast(unsigned short, (__bf16)f);
}

// XOR swizzle for the B tile in LDS (short-unit index).
// Base layout [kgi][n][8]: writes have n-stride 4 across lanes -> 64B stride
// -> 32-way bank conflict. XOR short-index bits 4..5 with n bits 3..4
// (write side: lm>>1) spreads the 64 lanes to 2-way (free). Read side uses
// the same formula -> bijective, 16B alignment preserved (bits 0..3 untouched).
__device__ inline int bswz(int kgi, int n) {
    return (kgi * 512 + n * 8) ^ (((n >> 3) & 3) << 4);
}

// ---------------------------------------------------------------------------
// Kernel 1 (setup): 48 independent blocks instead of 16 serial-phase blocks.
//   blocks  0..15 : Wf -> bf16 fragment-major ws_A   (column group = blockIdx)
//   blocks 16..31 : per-batch kl math + softmax -> ws_kld[b]  (no atomics)
//   blocks 32..47 : per-batch bias GEMV -> ws_bias
// The three roles have no mutual dependence; previously they ran serially
// inside one block per batch on 16 CUs.
// ---------------------------------------------------------------------------
__global__ __launch_bounds__(256) void setup_kernel(
    const float* __restrict__ mu_prior,   // (16,128,32)
    const float* __restrict__ ls_prior,   // (16,128,32)
    const float* __restrict__ pi_prior,   // (16,32)
    const float* __restrict__ mu_post,    // (16,128)
    const float* __restrict__ ls_post,    // (16,128)
    const float* __restrict__ noise_c,    // (16,128)
    const float* __restrict__ noise_z,    // (16,128)
    const float* __restrict__ projW,      // (256,384)
    const float* __restrict__ projb,      // (256,)
    float* __restrict__ ws_bias,          // (16,256)
    short* __restrict__ ws_A,             // (32,256,8) bf16 fragment-major
    float* __restrict__ ws_kld)           // (16,) per-batch partials
{
    const int g = blockIdx.x;
    const int t = threadIdx.x;  // 0..255

    __shared__ float s_zpost[128];
    __shared__ float s_zc[128];
    __shared__ float s_mu[128];
    __shared__ float s_e2[128];
    __shared__ float s_lsp[128];
    __shared__ float s_kstd[128];
    __shared__ float s_p1[8][32];
    __shared__ float s_p2[8][32];

    if (g < 16) {
        // ---- role A: Wf columns g*16..g*16+15 -> ws_A fragments ----
        const float* wrow = projW + t * 384 + g * 16;
        bf16x8 w0, w1;
#pragma unroll
        for (int j = 0; j < 8; ++j) w0[j] = f2bf(wrow[j]);
#pragma unroll
        for (int j = 0; j < 8; ++j) w1[j] = f2bf(wrow[8 + j]);
        *(bf16x8*)&ws_A[(g * 2 + 0) * 2048 + t * 8] = w0;
        *(bf16x8*)&ws_A[(g * 2 + 1) * 2048 + t * 8] = w1;
        return;
    }

    if (g < 32) {
        // ---- role B: per-batch kl math, softmax, kld partial ----
        const int b = g - 16;
        if (t < 128) {
            const float mu = mu_post[b * 128 + t];
            const float ls = ls_post[b * 128 + t];
            const float el = __expf(ls);
            s_zpost[t] = mu + el * noise_c[b * 128 + t];
            s_mu[t]    = mu;
            s_e2[t]    = el * el;
            s_lsp[t]   = ls;
            s_kstd[t]  = -ls + 0.5f * (el * el + mu * mu) - 0.5f;
        }
        __syncthreads();

        {
            const int c  = t & 31;
            const int gg = t >> 5;
            const float* mpB = mu_prior + b * 4096;
            const float* lpB = ls_prior + b * 4096;
            float lp = 0.f, kgv = 0.f;
#pragma unroll 4
            for (int j = 0; j < 16; ++j) {
                const int d = gg * 16 + j;
                const float mpr  = mpB[d * 32 + c];
                const float lpr  = lpB[d * 32 + c];
                const float inv2 = 0.5f * __expf(-2.f * lpr);
                const float zd   = s_zpost[d] - mpr;
                lp += -lpr - 0.91893853320467274f - zd * zd * inv2;
                const float dm   = s_mu[d] - mpr;
                const float e2pr = __expf(2.f * lpr);
                kgv += lpr - s_lsp[d]
                     + (s_e2[d] + dm * dm) * __builtin_amdgcn_rcpf(2.f * e2pr + EPS_F)
                     - 0.5f;
            }
            s_p1[gg][c] = lp;
            s_p2[gg][c] = kgv;
        }
        __syncthreads();

        if (t < 64) {
            const int c = t & 31;
            float lp = 0.f, kgv = 0.f;
#pragma unroll
            for (int gg = 0; gg < 8; ++gg) { lp += s_p1[gg][c]; kgv += s_p2[gg][c]; }
            float ks = s_kstd[c] + s_kstd[c + 32] + s_kstd[c + 64] + s_kstd[c + 96];
            const float pp = pi_prior[b * 32 + c];

            float m = lp;
#pragma unroll
            for (int o = 16; o; o >>= 1) m = fmaxf(m, __shfl_xor(m, o, 32));
            const float e = __expf(lp - m);
            float den = e;
#pragma unroll
            for (int o = 16; o; o >>= 1) den += __shfl_xor(den, o, 32);
            const float pi = e * __builtin_amdgcn_rcpf(den);
            float tot = pi * kgv + pi * (__logf(pi + EPS_F) - __logf(pp + EPS_F));
#pragma unroll
            for (int o = 16; o; o >>= 1) tot += __shfl_xor(tot, o, 32);
#pragma unroll
            for (int o = 16; o; o >>= 1) ks += __shfl_xor(ks, o, 32);
            if (t == 0) ws_kld[b] = tot + ks;   // plain store; gemm finalizes
        }
        return;
    }

    // ---- role C: per-batch bias GEMV ----
    {
        const int b = g - 32;
        if (t < 128) {
            const float mu = mu_post[b * 128 + t];
            const float el = __expf(ls_post[b * 128 + t]);
            s_zc[t] = mu + (el + EPS_F) * noise_z[b * 128 + t];
        }
        __syncthreads();

        const float4* wrow = (const float4*)(projW + t * 384 + 256);
        float sum = projb[t];
#pragma unroll 8
        for (int j = 0; j < 32; ++j) {
            const float4 w = wrow[j];
            sum += s_zc[4 * j + 0] * w.x + s_zc[4 * j + 1] * w.y +
                   s_zc[4 * j + 2] * w.z + s_zc[4 * j + 3] * w.w;
        }
        ws_bias[b * 256 + t] = sum;
    }
}

// ---------------------------------------------------------------------------
// Kernel 2: bf16 MFMA GEMM, single-barrier structure (kept) with:
//   * XOR-swizzled B-LDS (write conflict 32-way -> 2-way, reads unchanged)
//   * HW cvt_pk bf16 conversion in staging
//   * swapped MFMA operands (A<->B lane layouts are symmetric for 16x16x32)
//     -> C fragment transposed -> each lane owns 4 consecutive n
//     -> epilogue is 16 dwordx4 stores instead of 64 dword stores
//   * __launch_bounds__(256,4) pins 4 blocks/CU so the 1024-block grid runs
//     in exactly one residency round (LDS 33KB <= 40KB, VGPR fits 128)
//   * kld finalize folded into block (0,0) -> memset + atomicAdd dispatches gone
// ---------------------------------------------------------------------------
__global__ __launch_bounds__(256, 4) void gemm_kernel(
    const float* __restrict__ F,       // (16,256,4096) fp32
    const short* __restrict__ wsA,     // (32,256,8) bf16 fragment-major
    const float* __restrict__ bias,    // (16,256)
    const float* __restrict__ ws_kld,  // (16,)
    float* __restrict__ O)             // (16,256,4096) + kld at [16777216]
{
    const int nT = blockIdx.x;  // 0..63  (HW tiles of 64)
    const int b  = blockIdx.y;  // 0..15

    __shared__ short Bl[32 * 64 * 8];  // swizzled [kgi][n][8], 32 KB
    __shared__ float s_bias[256];

    const int tid  = threadIdx.x;
    const int lane = tid & 63;
    const int wave = tid >> 6;  // 0..3  (M offset wave*64)
    const int kg   = lane >> 4; // 0..3
    const int lm   = lane & 15;

    s_bias[tid] = bias[b * 256 + tid];

    if (nT == 0 && b == 0 && tid == 0) {
        float s = 0.f;
#pragma unroll
        for (int i = 0; i < 16; ++i) s += ws_kld[i];
        O[16777216] = s * 0.0625f;
    }

    // ---- stage full B tile: thread covers 16 k's x 4 n's ----
    const int sn4 = (tid & 15) * 4;      // n offset, 4 cols
    const int skb = (tid >> 4) * 16;     // k base, 16 rows
    const float* fp = F + (size_t)b * 1048576 + (size_t)skb * 4096
                    + nT * 64 + sn4;

    float4 ld[16];
#pragma unroll
    for (int i = 0; i < 16; ++i)
        ld[i] = *(const float4*)(fp + (size_t)i * 4096);

#pragma unroll
    for (int h = 0; h < 2; ++h) {        // two kg groups of 8 k's
        const int kgi = (skb >> 3) + h;
#pragma unroll
        for (int c = 0; c < 4; ++c) {    // 4 n's
            bf16x8 v;
#pragma unroll
            for (int j = 0; j < 8; ++j) {
                const float4 q = ld[h * 8 + j];
                v[j] = f2bf(c == 0 ? q.x : c == 1 ? q.y : c == 2 ? q.z : q.w);
            }
            *(bf16x8*)&Bl[bswz(kgi, sn4 + c)] = v;
        }
    }
    __syncthreads();  // the ONLY barrier

    // ---- K loop: all-LDS B, L2 A, no barriers ----
    const short* aBase = wsA + (size_t)kg * 2048 + (wave * 64 + lm) * 8;

    f32x4 acc[4][4];
#pragma unroll
    for (int i = 0; i < 4; ++i)
#pragma unroll
        for (int j = 0; j < 4; ++j) acc[i][j] = (f32x4){0.f, 0.f, 0.f, 0.f};

#pragma unroll
    for (int kc = 0; kc < 8; ++kc) {
        bf16x8 aW[4], bF[4];
#pragma unroll
        for (int mt = 0; mt < 4; ++mt)
            aW[mt] = *(const bf16x8*)(aBase + (size_t)kc * 8192 + mt * 128);
#pragma unroll
        for (int nt = 0; nt < 4; ++nt)
            bF[nt] = *(const bf16x8*)&Bl[bswz(kc * 4 + kg, nt * 16 + lm)];

        // operands SWAPPED vs r5: A-slot = F fragment, B-slot = W fragment.
        // D'[row][col] = sum_k F[k][nbase+row] * W[mbase+col][k]
        // lane (kg,lm), reg r: n = nbase + kg*4 + r, m = mbase + lm
#pragma unroll
        for (int mt = 0; mt < 4; ++mt)
#pragma unroll
            for (int nt = 0; nt < 4; ++nt)
                acc[mt][nt] = __builtin_amdgcn_mfma_f32_16x16x32_bf16(
                    bF[nt], aW[mt], acc[mt][nt], 0, 0, 0);
    }

    // ---- epilogue: + bias, vectorized dwordx4 stores ----
    // lane holds O[m = wave*64+mt*16+lm][n = nT*64 + nt*16 + kg*4 + r], r=0..3
    float* Ob = O + (size_t)b * 1048576 + nT * 64 + kg * 4;
#pragma unroll
    for (int mt = 0; mt < 4; ++mt) {
        const int m = wave * 64 + mt * 16 + lm;
        const float bb = s_bias[m];
        float* orow = Ob + (size_t)m * 4096;
#pragma unroll
        for (int nt = 0; nt < 4; ++nt) {
            float4 o4;
            o4.x = acc[mt][nt][0] + bb;
            o4.y = acc[mt][nt][1] + bb;
            o4.z = acc[mt][nt][2] + bb;
            o4.w = acc[mt][nt][3] + bb;
            *(float4*)(orow + nt * 16) = o4;
        }
    }
}

extern "C" void kernel_launch(void* const* d_in, const int* in_sizes, int n_in,
                              void* d_out, int out_size, void* d_ws, size_t ws_size,
                              hipStream_t stream) {
    const float* f_curr   = (const float*)d_in[0];  // (16,256,64,64)
    const float* mu_prior = (const float*)d_in[1];  // (16,128,32)
    const float* ls_prior = (const float*)d_in[2];  // (16,128,32)
    const float* pi_prior = (const float*)d_in[3];  // (16,32)
    const float* mu_post  = (const float*)d_in[4];  // (16,128)
    const float* ls_post  = (const float*)d_in[5];  // (16,128)
    const float* noise_c  = (const float*)d_in[6];  // (16,128)
    const float* noise_z  = (const float*)d_in[7];  // (16,128)
    const float* projW    = (const float*)d_in[8];  // (256,384)
    const float* projb    = (const float*)d_in[9];  // (256,)

    float* out = (float*)d_out;            // 16*256*64*64 f_out + 1 kld
    float* ws  = (float*)d_ws;
    float* ws_bias = ws;                   // 4096 floats
    short* ws_A    = (short*)(ws + 4096);  // 32*256*8 bf16 (128 KB)
    float* ws_kld  = ws + 4096 + 32768;    // 16 floats

    setup_kernel<<<48, 256, 0, stream>>>(mu_prior, ls_prior, pi_prior, mu_post,
                                         ls_post, noise_c, noise_z, projW, projb,
                                         ws_bias, ws_A, ws_kld);
    gemm_kernel<<<dim3(64, 16), 256, 0, stream>>>(f_curr, ws_A, ws_bias, ws_kld, out);
}